// Round 7
// baseline (214.106 us; speedup 1.0000x reference)
//
#include <hip/hip_runtime.h>
#include <hip/hip_bf16.h>

// Problem constants
// B=64, C=4, H=256, W=256; SCALES=(8,16,32); windows=(0,250,500,750,1000)
// KEY_INT = 0x5D1CE5 = 6102245
// base_core = (KEY_INT * 2654435761) % 10007  (product ~1.62e19 fits in u64)
static constexpr int KEY_MUL =
    (int)((6102245ULL * 2654435761ULL) % 10007ULL);
static constexpr int HASH_MOD = 10007;

typedef float f32x4 __attribute__((ext_vector_type(4)));

// ---------------------------------------------------------------------------
// Fused persistent kernel. nb blocks x 256 threads, 8 blocks/CU pinned
// (launch_bounds caps VGPR at 64 so 2048 blocks are co-resident at nb=2048).
//
// Phase 1 (pool): work item wi in [0,2048): ch = wi&31 (8-plane chunk),
//   half = (wi>>5)&1, pr = wi>>6. Sums 8 planes x 8 rows x 128 cols ->
//   16 patch partials -> ws_partial[(pr*32 + half*16 + pc)*32 + ch].
//
// Pre-issue: 8 noise float4 loads for this block's first slab, so HBM
//   latency hides inside the barrier wait.
//
// Grid barrier: __threadfence + device-scope atomicAdd + spin (NOT cg --
//   cg::grid_sync measured ~370us in round 3; this raw join is ~us-scale).
//   Counter is memset to 0 by the launcher each call (deterministic).
//
// Phase 2 (bias+add): slab wi2: plane = wi2>>3, q = wi2&7 -> rows
//   [q*32,q*32+32). t<128 reduce partials -> s8 -> combined bias btot[128];
//   all 256 threads add+store 8 float4 (already loaded).
// ---------------------------------------------------------------------------
__global__ __launch_bounds__(256, 8) void fused32(
    const float* __restrict__ noise, const float* __restrict__ latent,
    const int* __restrict__ tstep, float* __restrict__ out,
    float* __restrict__ ws_partial, unsigned int* __restrict__ cnt) {
  const int t = threadIdx.x;
  const int NB = gridDim.x;

  __shared__ float red[8][16];
  __shared__ float s8[128];
  __shared__ float btot[128];

  // ---------------- Phase 1: pool latent -> partials ----------------
  for (int wi = blockIdx.x; wi < 2048; wi += NB) {
    const int ch = wi & 31;
    const int half = (wi >> 5) & 1;
    const int pr = wi >> 6;
    const int cl = t & 31;  // float4 col within 128-col half
    const int rg = t >> 5;  // image row 0..7 within patch row
    const float4* base = reinterpret_cast<const float4*>(latent);
    float4 pv[8];
#pragma unroll
    for (int pl = 0; pl < 8; ++pl)
      pv[pl] = base[(size_t)(ch * 8 + pl) * 16384 + (pr * 8 + rg) * 64 +
                    half * 32 + cl];
    float acc = 0.0f;
#pragma unroll
    for (int pl = 0; pl < 8; ++pl)
      acc += (pv[pl].x + pv[pl].y) + (pv[pl].z + pv[pl].w);
    acc += __shfl_xor(acc, 1, 64);  // lanes 2c,2c+1 share an 8-wide patch col
    if ((cl & 1) == 0) red[rg][cl >> 1] = acc;
    __syncthreads();
    if (t < 16) {
      float s = ((red[0][t] + red[1][t]) + (red[2][t] + red[3][t])) +
                ((red[4][t] + red[5][t]) + (red[6][t] + red[7][t]));
      ws_partial[(pr * 32 + half * 16 + t) * 32 + ch] = s;
    }
    __syncthreads();
  }

  // ------- pre-issue first slab's noise loads (hide under barrier) -------
  int wi2 = blockIdx.x;
  const f32x4* __restrict__ n4all = reinterpret_cast<const f32x4*>(noise);
  f32x4* __restrict__ o4all = reinterpret_cast<f32x4*>(out);
  size_t slab = (size_t)(wi2 >> 3) * 16384 + (size_t)(wi2 & 7) * 2048;
  f32x4 v[8];
#pragma unroll
  for (int k = 0; k < 8; ++k) v[k] = n4all[slab + k * 256 + t];
  const int ts = *tstep;

  // ---------------- grid barrier (device-scope atomic join) ----------------
  if (t == 0) {
    __threadfence();  // release this block's partial stores device-wide
    __hip_atomic_fetch_add(cnt, 1u, __ATOMIC_ACQ_REL, __HIP_MEMORY_SCOPE_AGENT);
    unsigned iter = 0;
    while (__hip_atomic_load(cnt, __ATOMIC_ACQUIRE, __HIP_MEMORY_SCOPE_AGENT) <
           (unsigned)NB) {
      __builtin_amdgcn_s_sleep(2);
      if (++iter > 100000000u) break;  // safety valve: loud-fail, not hang
    }
    __threadfence();  // acquire side
  }
  __syncthreads();

  // ---------------- Phase 2: bias + stream-add ----------------
  while (true) {
    const int q = wi2 & 7;  // 32-row slab index within plane

    if (t < 128) {  // reduce this slab's patch partials (L2-broadcast reads)
      const int lr = t >> 5, lc = t & 31;
      const int patch = (4 * q + lr) * 32 + lc;
      const float4* p4 = reinterpret_cast<const float4*>(ws_partial) + patch * 8;
      float s = 0.0f;
#pragma unroll
      for (int c = 0; c < 8; ++c) {
        float4 w = p4[c];
        s += (w.x + w.y) + (w.z + w.w);
      }
      s8[t] = s;
    }
    __syncthreads();

    if (t < 128) {
      const int lr = t >> 5, lc = t & 31;
      const int pr = 4 * q + lr;  // global patch-8 row

      int bucket = -1;  // searchsorted(windows,'right') - 1
      const int wins[5] = {0, 250, 500, 750, 1000};
#pragma unroll
      for (int k = 0; k < 5; ++k) bucket += (ts >= wins[k]) ? 1 : 0;

      const float expo = expf((float)(-ts) * 0.001f);
      const float phase_k = (float)(6.2831853 / 10007.0);

      float bias = 0.0f;
      // ---- scale 8 ----
      {
        const int bb = (KEY_MUL + 8 * 97 + bucket * 139) % HASH_MOD;
        const int h = (bb + pr * (8 * 131) + lc * (8 * 137)) % HASH_MOD;
        const float pooled = s8[t] * (1.0f / 16384.0f);  // /(B*C*64)
        bias += cosf(pooled * 3.0f + (float)h * phase_k) *
                (0.0176776695296637f * expo);  // 0.05/sqrt(8)
      }
      // ---- scale 16 (2x2 aggregate of s8) ----
      {
        const int bb = (KEY_MUL + 16 * 97 + bucket * 139) % HASH_MOD;
        const int h =
            (bb + (pr >> 1) * (16 * 131) + (lc >> 1) * (16 * 137)) % HASH_MOD;
        const int r0 = (lr & ~1) * 32, c0 = lc & ~1;
        const float s = (s8[r0 + c0] + s8[r0 + c0 + 1]) +
                        (s8[r0 + 32 + c0] + s8[r0 + 32 + c0 + 1]);
        const float pooled = s * (1.0f / 65536.0f);  // /(B*C*256)
        bias += cosf(pooled * 3.0f + (float)h * phase_k) *
                (0.0125f * expo);  // 0.05/sqrt(16)
      }
      // ---- scale 32 (4x4 aggregate; 32-row patch == this slab) ----
      {
        const int bb = (KEY_MUL + 32 * 97 + bucket * 139) % HASH_MOD;
        const int h = (bb + q * (32 * 131) + (lc >> 2) * (32 * 137)) % HASH_MOD;
        const int c0 = lc & ~3;
        float s = 0.0f;
#pragma unroll
        for (int di = 0; di < 4; ++di)
#pragma unroll
          for (int dj = 0; dj < 4; ++dj) s += s8[di * 32 + c0 + dj];
        const float pooled = s * (1.0f / 262144.0f);  // /(B*C*1024)
        bias += cosf(pooled * 3.0f + (float)h * phase_k) *
                (0.00883883476483184f * expo);  // 0.05/sqrt(32)
      }
      btot[t] = bias;
    }
    __syncthreads();

    // ---- add + store (loads already resident) ----
    {
      const int c8 = (t & 63) >> 1;
      const int r0 = t >> 6;
#pragma unroll
      for (int k = 0; k < 8; ++k) {
        const int lrow = k * 4 + r0;  // local row 0..31
        const float bs = btot[(lrow >> 3) * 32 + c8];
        f32x4 w = v[k];
        w.x += bs; w.y += bs; w.z += bs; w.w += bs;
        o4all[slab + k * 256 + t] = w;
      }
    }

    wi2 += NB;
    if (wi2 >= 2048) break;  // single iteration when NB == 2048
    __syncthreads();         // protect s8/btot reuse
    slab = (size_t)(wi2 >> 3) * 16384 + (size_t)(wi2 & 7) * 2048;
#pragma unroll
    for (int k = 0; k < 8; ++k) v[k] = n4all[slab + k * 256 + t];
  }
}

// ---------------------------------------------------------------------------
// Fallback two-kernel path (round-6 structure) for small workspaces.
// ---------------------------------------------------------------------------
template <int NCH>
__global__ __launch_bounds__(256) void pool_kernel_legacy(
    const float* __restrict__ latent, float* __restrict__ ws_partial) {
  constexpr int PPC = 256 / NCH;
  const int pr = blockIdx.y, ch = blockIdx.x, t = threadIdx.x;
  const int cl = t & 63, rg = t >> 6;
  float acc = 0.0f;
  const float4* base = reinterpret_cast<const float4*>(latent);
#pragma unroll 8
  for (int pl = 0; pl < PPC; ++pl) {
    const float4* prow = base + (size_t)(ch * PPC + pl) * 16384;
#pragma unroll
    for (int rr = 0; rr < 2; ++rr) {
      float4 v = prow[(pr * 8 + rg + rr * 4) * 64 + cl];
      acc += (v.x + v.y) + (v.z + v.w);
    }
  }
  acc += __shfl_xor(acc, 1, 64);
  __shared__ float lds[4][32];
  if ((cl & 1) == 0) lds[rg][cl >> 1] = acc;
  __syncthreads();
  if (t < 32) {
    float s = (lds[0][t] + lds[1][t]) + (lds[2][t] + lds[3][t]);
    ws_partial[(pr * 32 + t) * NCH + ch] = s;
  }
}

template <int NCH>
__global__ __launch_bounds__(256, 8) void bias_add_kernel(
    const float* __restrict__ noise, const float* __restrict__ ws_partial,
    const int* __restrict__ tstep, float* __restrict__ out) {
  const int t = threadIdx.x;
  const int b = blockIdx.x;
  const int q = b & 7;

  __shared__ float s8[128];
  __shared__ float btot[128];

  const size_t slab = (size_t)(b >> 3) * 16384 + (size_t)q * 2048;
  const f32x4* __restrict__ n4 = reinterpret_cast<const f32x4*>(noise) + slab;
  f32x4* __restrict__ o4 = reinterpret_cast<f32x4*>(out) + slab;

  f32x4 v[8];
#pragma unroll
  for (int k = 0; k < 8; ++k) v[k] = n4[k * 256 + t];

  const int ts = *tstep;

  if (t < 128) {
    const int lr = t >> 5, lc = t & 31;
    const int patch = (4 * q + lr) * 32 + lc;
    float s = 0.0f;
#pragma unroll
    for (int c = 0; c < NCH; ++c) s += ws_partial[patch * NCH + c];
    s8[t] = s;
  }
  __syncthreads();

  if (t < 128) {
    const int lr = t >> 5, lc = t & 31;
    const int pr = 4 * q + lr;
    int bucket = -1;
    const int wins[5] = {0, 250, 500, 750, 1000};
#pragma unroll
    for (int k = 0; k < 5; ++k) bucket += (ts >= wins[k]) ? 1 : 0;
    const float expo = expf((float)(-ts) * 0.001f);
    const float phase_k = (float)(6.2831853 / 10007.0);
    float bias = 0.0f;
    {
      const int bb = (KEY_MUL + 8 * 97 + bucket * 139) % HASH_MOD;
      const int h = (bb + pr * (8 * 131) + lc * (8 * 137)) % HASH_MOD;
      bias += cosf(s8[t] * (1.0f / 16384.0f) * 3.0f + (float)h * phase_k) *
              (0.0176776695296637f * expo);
    }
    {
      const int bb = (KEY_MUL + 16 * 97 + bucket * 139) % HASH_MOD;
      const int h =
          (bb + (pr >> 1) * (16 * 131) + (lc >> 1) * (16 * 137)) % HASH_MOD;
      const int r0 = (lr & ~1) * 32, c0 = lc & ~1;
      const float s = (s8[r0 + c0] + s8[r0 + c0 + 1]) +
                      (s8[r0 + 32 + c0] + s8[r0 + 32 + c0 + 1]);
      bias += cosf(s * (1.0f / 65536.0f) * 3.0f + (float)h * phase_k) *
              (0.0125f * expo);
    }
    {
      const int bb = (KEY_MUL + 32 * 97 + bucket * 139) % HASH_MOD;
      const int h = (bb + q * (32 * 131) + (lc >> 2) * (32 * 137)) % HASH_MOD;
      const int c0 = lc & ~3;
      float s = 0.0f;
#pragma unroll
      for (int di = 0; di < 4; ++di)
#pragma unroll
        for (int dj = 0; dj < 4; ++dj) s += s8[di * 32 + c0 + dj];
      bias += cosf(s * (1.0f / 262144.0f) * 3.0f + (float)h * phase_k) *
              (0.00883883476483184f * expo);
    }
    btot[t] = bias;
  }
  __syncthreads();

  {
    const int c8 = (t & 63) >> 1;
    const int r0 = t >> 6;
#pragma unroll
    for (int k = 0; k < 8; ++k) {
      const int lrow = k * 4 + r0;
      const float bs = btot[(lrow >> 3) * 32 + c8];
      f32x4 w = v[k];
      w.x += bs; w.y += bs; w.z += bs; w.w += bs;
      o4[k * 256 + t] = w;
    }
  }
}

extern "C" void kernel_launch(void* const* d_in, const int* in_sizes, int n_in,
                              void* d_out, int out_size, void* d_ws, size_t ws_size,
                              hipStream_t stream) {
  const float* noise  = (const float*)d_in[0];
  const float* latent = (const float*)d_in[1];
  const int*   tstep  = (const int*)d_in[2];
  float* out = (float*)d_out;
  float* ws  = (float*)d_ws;

  const size_t partials_bytes = (size_t)1024 * 32 * sizeof(float);  // 128 KiB
  const size_t need_fused = partials_bytes + 16;                    // + counter

  if (ws_size >= need_fused) {
    unsigned int* cnt =
        reinterpret_cast<unsigned int*>((char*)d_ws + partials_bytes);
    int occ = 0, nb = 2048;
    if (hipOccupancyMaxActiveBlocksPerMultiprocessor(&occ, fused32, 256, 0) ==
            hipSuccess &&
        occ > 0) {
      const int cap = occ * 256;  // occ blocks/CU x 256 CUs
      nb = cap < 2048 ? cap : 2048;
    }
    hipMemsetAsync(cnt, 0, sizeof(unsigned int), stream);
    fused32<<<nb, 256, 0, stream>>>(noise, latent, tstep, out, ws, cnt);
  } else if (ws_size >= partials_bytes) {
    // round-6 two-kernel path, NCH=32 partial layout via legacy pool
    pool_kernel_legacy<32><<<dim3(32, 32), 256, 0, stream>>>(latent, ws);
    bias_add_kernel<32><<<2048, 256, 0, stream>>>(noise, ws, tstep, out);
  } else {
    pool_kernel_legacy<1><<<dim3(1, 32), 256, 0, stream>>>(latent, ws);
    bias_add_kernel<1><<<2048, 256, 0, stream>>>(noise, ws, tstep, out);
  }
}

// Round 8
// 43.299 us; speedup vs baseline: 4.9448x; 4.9448x over previous
//
#include <hip/hip_runtime.h>
#include <hip/hip_bf16.h>

// Problem constants
// B=64, C=4, H=256, W=256; SCALES=(8,16,32); windows=(0,250,500,750,1000)
// KEY_INT = 0x5D1CE5 = 6102245
// base_core = (KEY_INT * 2654435761) % 10007  (product ~1.62e19 fits in u64)
static constexpr int KEY_MUL =
    (int)((6102245ULL * 2654435761ULL) % 10007ULL);
static constexpr int HASH_MOD = 10007;

typedef float f32x4 __attribute__((ext_vector_type(4)));

// ---------------------------------------------------------------------------
// Kernel 1 (main path, NCH=32): pool latent -> per-chunk partials of 8x8
// patches. grid = (32 chunks, 64 half-rows), block = 256, 8 blocks/CU.
// Block (ch, hr): pr = hr>>1, half = hr&1; sums 8 planes x 8 rows x 128 cols
// -> 16 patch partials -> ws_partial[(pr*32 + half*16 + pc)*32 + ch].
// 8 nontemporal f32x4 loads fully in flight per thread (latent is
// single-use per replay; don't pollute L2 -- L3 is memory-side anyway).
// ---------------------------------------------------------------------------
__global__ __launch_bounds__(256, 8) void pool_kernel32(
    const float* __restrict__ latent, float* __restrict__ ws_partial) {
  const int ch = blockIdx.x;        // plane chunk (8 planes)
  const int pr = blockIdx.y >> 1;   // patch row 0..31
  const int half = blockIdx.y & 1;  // column half
  const int t = threadIdx.x;
  const int cl = t & 31;  // f32x4 col within half
  const int rg = t >> 5;  // image row 0..7 within patch row

  const f32x4* base = reinterpret_cast<const f32x4*>(latent);
  f32x4 v[8];
#pragma unroll
  for (int pl = 0; pl < 8; ++pl)
    v[pl] = __builtin_nontemporal_load(
        &base[(size_t)(ch * 8 + pl) * 16384 + (pr * 8 + rg) * 64 + half * 32 +
              cl]);
  float acc = 0.0f;
#pragma unroll
  for (int pl = 0; pl < 8; ++pl)
    acc += (v[pl].x + v[pl].y) + (v[pl].z + v[pl].w);
  acc += __shfl_xor(acc, 1, 64);  // lanes 2c,2c+1 share an 8-wide patch col

  __shared__ float lds[8][16];
  if ((cl & 1) == 0) lds[rg][cl >> 1] = acc;
  __syncthreads();
  if (t < 16) {
    float s = ((lds[0][t] + lds[1][t]) + (lds[2][t] + lds[3][t])) +
              ((lds[4][t] + lds[5][t]) + (lds[6][t] + lds[7][t]));
    ws_partial[(pr * 32 + half * 16 + t) * 32 + ch] = s;
  }
}

// Legacy pool for small-ws fallback: grid (NCH, 32), PPC planes per chunk.
template <int NCH>
__global__ __launch_bounds__(256) void pool_kernel_legacy(
    const float* __restrict__ latent, float* __restrict__ ws_partial) {
  constexpr int PPC = 256 / NCH;
  const int pr = blockIdx.y, ch = blockIdx.x, t = threadIdx.x;
  const int cl = t & 63, rg = t >> 6;
  float acc = 0.0f;
  const float4* base = reinterpret_cast<const float4*>(latent);
#pragma unroll 8
  for (int pl = 0; pl < PPC; ++pl) {
    const float4* prow = base + (size_t)(ch * PPC + pl) * 16384;
#pragma unroll
    for (int rr = 0; rr < 2; ++rr) {
      float4 v = prow[(pr * 8 + rg + rr * 4) * 64 + cl];
      acc += (v.x + v.y) + (v.z + v.w);
    }
  }
  acc += __shfl_xor(acc, 1, 64);
  __shared__ float lds[4][32];
  if ((cl & 1) == 0) lds[rg][cl >> 1] = acc;
  __syncthreads();
  if (t < 32) {
    float s = (lds[0][t] + lds[1][t]) + (lds[2][t] + lds[3][t]);
    ws_partial[(pr * 32 + t) * NCH + ch] = s;
  }
}

// ---------------------------------------------------------------------------
// Kernel 2: bias build + stream add. 1024 blocks x 256 threads.
// Block b: plane = b>>2, q = b&3 -> rows [q*64, q*64+64) = 8 patch-8 rows.
// Thread t = (lr = t>>5, lc = t&31) owns patch (8q+lr, lc) -- exactly 256
// patches per slab, no idle threads.
//
// Load ordering (in-order vmcnt): partial loads issued FIRST, then the 16
// noise loads. Consuming the partials waits vmcnt(16), so all 16 noise
// loads remain in flight through the reduce + cosf bias phase (T14).
// Noise loads are nontemporal (single-use; skip L2). Stores are normal
// (let the memory-side Infinity Cache absorb out rewrites across replays).
// ---------------------------------------------------------------------------
template <int NCH>
__global__ __launch_bounds__(256, 4) void bias_add_kernel(
    const float* __restrict__ noise, const float* __restrict__ ws_partial,
    const int* __restrict__ tstep, float* __restrict__ out) {
  const int t = threadIdx.x;
  const int b = blockIdx.x;
  const int q = b & 3;    // 64-row slab index within plane
  const int lr = t >> 5;  // patch-8 row within slab, 0..7
  const int lc = t & 31;  // patch-8 col
  const int pr = 8 * q + lr;  // global patch-8 row

  __shared__ float s8[256];
  __shared__ float btot[256];

  // ---- 1. issue partial loads (needed first) ----
  const int patch = pr * 32 + lc;
  f32x4 pp[NCH >= 4 ? NCH / 4 : 1];
  float pp1[NCH >= 4 ? 1 : NCH];
  if constexpr (NCH >= 4) {
    const f32x4* p4 =
        reinterpret_cast<const f32x4*>(ws_partial) + patch * (NCH / 4);
#pragma unroll
    for (int c = 0; c < NCH / 4; ++c) pp[c] = p4[c];
  } else {
#pragma unroll
    for (int c = 0; c < NCH; ++c) pp1[c] = ws_partial[patch * NCH + c];
  }

  // ---- 2. issue all 16 noise loads (in flight through bias phase) ----
  const size_t slab = (size_t)(b >> 2) * 16384 + (size_t)q * 4096;
  const f32x4* __restrict__ n4 = reinterpret_cast<const f32x4*>(noise) + slab;
  f32x4* __restrict__ o4 = reinterpret_cast<f32x4*>(out) + slab;
  f32x4 v[16];
#pragma unroll
  for (int k = 0; k < 16; ++k)
    v[k] = __builtin_nontemporal_load(&n4[k * 256 + t]);

  const int ts = *tstep;

  // ---- 3. reduce partials -> s8 (waits vmcnt(16): noise still in flight) ----
  {
    float s = 0.0f;
    if constexpr (NCH >= 4) {
#pragma unroll
      for (int c = 0; c < NCH / 4; ++c)
        s += (pp[c].x + pp[c].y) + (pp[c].z + pp[c].w);
    } else {
#pragma unroll
      for (int c = 0; c < NCH; ++c) s += pp1[c];
    }
    s8[t] = s;
  }
  __syncthreads();

  // ---- 4. combined bias (g8 + g16 + g32) per patch ----
  {
    int bucket = -1;  // searchsorted(windows,'right') - 1 = count(w<=ts) - 1
    const int wins[5] = {0, 250, 500, 750, 1000};
#pragma unroll
    for (int k = 0; k < 5; ++k) bucket += (ts >= wins[k]) ? 1 : 0;

    const float expo = expf((float)(-ts) * 0.001f);
    const float phase_k = (float)(6.2831853 / 10007.0);

    float bias = 0.0f;
    // ---- scale 8 ----
    {
      const int bb = (KEY_MUL + 8 * 97 + bucket * 139) % HASH_MOD;
      const int h = (bb + pr * (8 * 131) + lc * (8 * 137)) % HASH_MOD;
      const float pooled = s8[t] * (1.0f / 16384.0f);  // /(B*C*64)
      bias += cosf(pooled * 3.0f + (float)h * phase_k) *
              (0.0176776695296637f * expo);  // 0.05/sqrt(8)
    }
    // ---- scale 16 (2x2 aggregate of s8) ----
    {
      const int bb = (KEY_MUL + 16 * 97 + bucket * 139) % HASH_MOD;
      const int h =
          (bb + (pr >> 1) * (16 * 131) + (lc >> 1) * (16 * 137)) % HASH_MOD;
      const int r0 = (lr & ~1) * 32, c0 = lc & ~1;
      const float s = (s8[r0 + c0] + s8[r0 + c0 + 1]) +
                      (s8[r0 + 32 + c0] + s8[r0 + 32 + c0 + 1]);
      const float pooled = s * (1.0f / 65536.0f);  // /(B*C*256)
      bias += cosf(pooled * 3.0f + (float)h * phase_k) *
              (0.0125f * expo);  // 0.05/sqrt(16)
    }
    // ---- scale 32 (4x4 aggregate of s8) ----
    {
      const int bb = (KEY_MUL + 32 * 97 + bucket * 139) % HASH_MOD;
      const int h =
          (bb + (pr >> 2) * (32 * 131) + (lc >> 2) * (32 * 137)) % HASH_MOD;
      const int r0 = (lr & ~3) * 32, c0 = lc & ~3;
      float s = 0.0f;
#pragma unroll
      for (int di = 0; di < 4; ++di)
#pragma unroll
        for (int dj = 0; dj < 4; ++dj) s += s8[r0 + di * 32 + c0 + dj];
      const float pooled = s * (1.0f / 262144.0f);  // /(B*C*1024)
      bias += cosf(pooled * 3.0f + (float)h * phase_k) *
              (0.00883883476483184f * expo);  // 0.05/sqrt(32)
    }
    btot[t] = bias;
  }
  __syncthreads();

  // ---- 5. add + store (noise loads resident by now) ----
  {
    const int c8 = (t & 63) >> 1;  // btot col
    const int r0 = t >> 6;         // row offset within 4-row step
#pragma unroll
    for (int k = 0; k < 16; ++k) {
      const int lrow = k * 4 + r0;  // local row 0..63
      const float bs = btot[(lrow >> 3) * 32 + c8];
      f32x4 w = v[k];
      w.x += bs; w.y += bs; w.z += bs; w.w += bs;
      o4[k * 256 + t] = w;
    }
  }
}

extern "C" void kernel_launch(void* const* d_in, const int* in_sizes, int n_in,
                              void* d_out, int out_size, void* d_ws, size_t ws_size,
                              hipStream_t stream) {
  const float* noise  = (const float*)d_in[0];
  const float* latent = (const float*)d_in[1];
  const int*   tstep  = (const int*)d_in[2];
  float* out = (float*)d_out;
  float* ws  = (float*)d_ws;

  const size_t need32 = (size_t)(1024 * 32) * sizeof(float);  // 128 KiB
  const size_t need1  = (size_t)1024 * sizeof(float);         // 4 KiB

  if (ws_size >= need32) {
    pool_kernel32<<<dim3(32, 64), 256, 0, stream>>>(latent, ws);
    bias_add_kernel<32><<<1024, 256, 0, stream>>>(noise, ws, tstep, out);
  } else if (ws_size >= need1) {
    pool_kernel_legacy<1><<<dim3(1, 32), 256, 0, stream>>>(latent, ws);
    bias_add_kernel<1><<<1024, 256, 0, stream>>>(noise, ws, tstep, out);
  } else {
    // no workspace: still correct via legacy path writing into out? Not
    // possible -- require at least 4 KiB (harness always provides ws).
    pool_kernel_legacy<1><<<dim3(1, 32), 256, 0, stream>>>(latent, ws);
    bias_add_kernel<1><<<1024, 256, 0, stream>>>(noise, ws, tstep, out);
  }
}

// Round 9
// 36.149 us; speedup vs baseline: 5.9229x; 1.1978x over previous
//
#include <hip/hip_runtime.h>
#include <hip/hip_bf16.h>

// Problem constants
// B=64, C=4, H=256, W=256; SCALES=(8,16,32); windows=(0,250,500,750,1000)
// KEY_INT = 0x5D1CE5 = 6102245
// base_core = (KEY_INT * 2654435761) % 10007  (product ~1.62e19 fits in u64)
static constexpr int KEY_MUL =
    (int)((6102245ULL * 2654435761ULL) % 10007ULL);
static constexpr int HASH_MOD = 10007;

typedef float f32x4 __attribute__((ext_vector_type(4)));

// ---------------------------------------------------------------------------
// ROUND-6 STRUCTURE (best measured: 36.2 us). Reverted from round 7/8
// experiments, both of which regressed:
//  - grid-wide join (cg or raw agent-scope atomics): 200-470 us on gfx950.
//  - nontemporal loads/stores: defeat L2/L3 reuse across graph replays
//    (round-5/6 profiles show ~half of noise served from cache; NT forced
//    full HBM traffic, +5-7 us).
//
// Kernel 1 (main path, NCH=32): pool latent -> per-chunk partials of 8x8
// patches. grid = (32 chunks, 64 half-rows), block = 256, 8 blocks/CU.
// Block (ch, hr): pr = hr>>1, half = hr&1; sums 8 planes x 8 rows x 128 cols
// -> 16 patch partials -> ws_partial[(pr*32 + half*16 + pc)*32 + ch].
// 8 float4 loads fully in flight per thread.
// ---------------------------------------------------------------------------
__global__ __launch_bounds__(256, 8) void pool_kernel32(
    const float* __restrict__ latent, float* __restrict__ ws_partial) {
  const int ch = blockIdx.x;        // plane chunk (8 planes)
  const int pr = blockIdx.y >> 1;   // patch row 0..31
  const int half = blockIdx.y & 1;  // column half
  const int t = threadIdx.x;
  const int cl = t & 31;  // float4 col within half
  const int rg = t >> 5;  // image row 0..7 within patch row

  const float4* base = reinterpret_cast<const float4*>(latent);
  float4 v[8];
#pragma unroll
  for (int pl = 0; pl < 8; ++pl)
    v[pl] = base[(size_t)(ch * 8 + pl) * 16384 + (pr * 8 + rg) * 64 +
                 half * 32 + cl];
  float acc = 0.0f;
#pragma unroll
  for (int pl = 0; pl < 8; ++pl) acc += (v[pl].x + v[pl].y) + (v[pl].z + v[pl].w);
  acc += __shfl_xor(acc, 1, 64);  // lanes 2c,2c+1 share an 8-wide patch col

  __shared__ float lds[8][16];
  if ((cl & 1) == 0) lds[rg][cl >> 1] = acc;
  __syncthreads();
  if (t < 16) {
    float s = ((lds[0][t] + lds[1][t]) + (lds[2][t] + lds[3][t])) +
              ((lds[4][t] + lds[5][t]) + (lds[6][t] + lds[7][t]));
    ws_partial[(pr * 32 + half * 16 + t) * 32 + ch] = s;
  }
}

// Legacy pool for small-ws fallback: grid (NCH, 32), PPC planes per chunk.
template <int NCH>
__global__ __launch_bounds__(256) void pool_kernel_legacy(
    const float* __restrict__ latent, float* __restrict__ ws_partial) {
  constexpr int PPC = 256 / NCH;
  const int pr = blockIdx.y, ch = blockIdx.x, t = threadIdx.x;
  const int cl = t & 63, rg = t >> 6;
  float acc = 0.0f;
  const float4* base = reinterpret_cast<const float4*>(latent);
#pragma unroll 8
  for (int pl = 0; pl < PPC; ++pl) {
    const float4* prow = base + (size_t)(ch * PPC + pl) * 16384;
#pragma unroll
    for (int rr = 0; rr < 2; ++rr) {
      float4 v = prow[(pr * 8 + rg + rr * 4) * 64 + cl];
      acc += (v.x + v.y) + (v.z + v.w);
    }
  }
  acc += __shfl_xor(acc, 1, 64);
  __shared__ float lds[4][32];
  if ((cl & 1) == 0) lds[rg][cl >> 1] = acc;
  __syncthreads();
  if (t < 32) {
    float s = (lds[0][t] + lds[1][t]) + (lds[2][t] + lds[3][t]);
    ws_partial[(pr * 32 + t) * NCH + ch] = s;
  }
}

// ---------------------------------------------------------------------------
// Kernel 2: bias build + stream add. 2048 blocks x 256 threads, 8 blocks/CU.
// Block b: plane = b>>3, q = b&7 -> rows [q*32, q*32+32) (4 patch-8 rows).
// T14 async-split: ALL 8 noise float4 loads are issued FIRST, so the
// partial-reduce + cosf bias phase runs under the HBM load latency.
// Threads t<128 reduce patch (4q + t>>5, t&31) partials -> s8 -> combined
// bias btot[128]; then all 256 threads add+store (normal stores; memory-side
// Infinity Cache absorbs out rewrites across graph replays).
// ---------------------------------------------------------------------------
template <int NCH>
__global__ __launch_bounds__(256, 8) void bias_add_kernel(
    const float* __restrict__ noise, const float* __restrict__ ws_partial,
    const int* __restrict__ tstep, float* __restrict__ out) {
  const int t = threadIdx.x;
  const int b = blockIdx.x;
  const int q = b & 7;  // 32-row slab index within plane

  __shared__ float s8[128];
  __shared__ float btot[128];

  const size_t slab = (size_t)(b >> 3) * 16384 + (size_t)q * 2048;
  const f32x4* __restrict__ n4 = reinterpret_cast<const f32x4*>(noise) + slab;
  f32x4* __restrict__ o4 = reinterpret_cast<f32x4*>(out) + slab;

  // ---- issue all noise loads up front (in flight during bias phase) ----
  f32x4 v[8];
#pragma unroll
  for (int k = 0; k < 8; ++k) v[k] = n4[k * 256 + t];

  const int ts = *tstep;

  if (t < 128) {
    const int lr = t >> 5;  // local patch-8 row 0..3
    const int lc = t & 31;  // patch-8 col
    const int patch = (4 * q + lr) * 32 + lc;
    float s = 0.0f;
    if constexpr (NCH >= 4) {
      const float4* p4 =
          reinterpret_cast<const float4*>(ws_partial) + patch * (NCH / 4);
#pragma unroll
      for (int c = 0; c < NCH / 4; ++c) {
        float4 w = p4[c];
        s += (w.x + w.y) + (w.z + w.w);
      }
    } else {
#pragma unroll
      for (int c = 0; c < NCH; ++c) s += ws_partial[patch * NCH + c];
    }
    s8[t] = s;
  }
  __syncthreads();

  if (t < 128) {
    const int lr = t >> 5;  // 0..3
    const int lc = t & 31;
    const int pr = 4 * q + lr;  // global patch-8 row

    // bucket = searchsorted(windows,'right') - 1 = count(w <= ts) - 1
    int bucket = -1;
    const int wins[5] = {0, 250, 500, 750, 1000};
#pragma unroll
    for (int k = 0; k < 5; ++k) bucket += (ts >= wins[k]) ? 1 : 0;

    const float expo = expf((float)(-ts) * 0.001f);
    const float phase_k = (float)(6.2831853 / 10007.0);

    float bias = 0.0f;
    // ---- scale 8 ----
    {
      const int bb = (KEY_MUL + 8 * 97 + bucket * 139) % HASH_MOD;
      const int h = (bb + pr * (8 * 131) + lc * (8 * 137)) % HASH_MOD;
      const float pooled = s8[t] * (1.0f / 16384.0f);  // /(B*C*64)
      bias += cosf(pooled * 3.0f + (float)h * phase_k) *
              (0.0176776695296637f * expo);  // 0.05/sqrt(8)
    }
    // ---- scale 16 (2x2 aggregate of s8) ----
    {
      const int bb = (KEY_MUL + 16 * 97 + bucket * 139) % HASH_MOD;
      const int h =
          (bb + (pr >> 1) * (16 * 131) + (lc >> 1) * (16 * 137)) % HASH_MOD;
      const int r0 = (lr & ~1) * 32, c0 = lc & ~1;
      const float s = (s8[r0 + c0] + s8[r0 + c0 + 1]) +
                      (s8[r0 + 32 + c0] + s8[r0 + 32 + c0 + 1]);
      const float pooled = s * (1.0f / 65536.0f);  // /(B*C*256)
      bias += cosf(pooled * 3.0f + (float)h * phase_k) *
              (0.0125f * expo);  // 0.05/sqrt(16)
    }
    // ---- scale 32 (4x4 aggregate of s8; 32-row patch == this slab) ----
    {
      const int bb = (KEY_MUL + 32 * 97 + bucket * 139) % HASH_MOD;
      const int h = (bb + q * (32 * 131) + (lc >> 2) * (32 * 137)) % HASH_MOD;
      const int c0 = lc & ~3;
      float s = 0.0f;
#pragma unroll
      for (int di = 0; di < 4; ++di)
#pragma unroll
        for (int dj = 0; dj < 4; ++dj) s += s8[di * 32 + c0 + dj];
      const float pooled = s * (1.0f / 262144.0f);  // /(B*C*1024)
      bias += cosf(pooled * 3.0f + (float)h * phase_k) *
              (0.00883883476483184f * expo);  // 0.05/sqrt(32)
    }
    btot[t] = bias;
  }
  __syncthreads();

  // ---- add + store (loads already resident) ----
  {
    const int c8 = (t & 63) >> 1;  // btot col
    const int r0 = t >> 6;         // row offset within 4-row step
#pragma unroll
    for (int k = 0; k < 8; ++k) {
      const int lrow = k * 4 + r0;  // local row 0..31
      const float bs = btot[(lrow >> 3) * 32 + c8];
      f32x4 w = v[k];
      w.x += bs; w.y += bs; w.z += bs; w.w += bs;
      o4[k * 256 + t] = w;
    }
  }
}

extern "C" void kernel_launch(void* const* d_in, const int* in_sizes, int n_in,
                              void* d_out, int out_size, void* d_ws, size_t ws_size,
                              hipStream_t stream) {
  const float* noise  = (const float*)d_in[0];
  const float* latent = (const float*)d_in[1];
  const int*   tstep  = (const int*)d_in[2];
  float* out = (float*)d_out;
  float* ws  = (float*)d_ws;

  const size_t need32 = (size_t)(1024 * 32) * sizeof(float);  // 128 KiB
  const size_t need8  = (size_t)(1024 * 8) * sizeof(float);   // 32 KiB

  if (ws_size >= need32) {
    pool_kernel32<<<dim3(32, 64), 256, 0, stream>>>(latent, ws);
    bias_add_kernel<32><<<2048, 256, 0, stream>>>(noise, ws, tstep, out);
  } else if (ws_size >= need8) {
    pool_kernel_legacy<8><<<dim3(8, 32), 256, 0, stream>>>(latent, ws);
    bias_add_kernel<8><<<2048, 256, 0, stream>>>(noise, ws, tstep, out);
  } else {
    pool_kernel_legacy<1><<<dim3(1, 32), 256, 0, stream>>>(latent, ws);
    bias_add_kernel<1><<<2048, 256, 0, stream>>>(noise, ws, tstep, out);
  }
}